// Round 8
// baseline (226.304 us; speedup 1.0000x reference)
//
#include <hip/hip_runtime.h>
#include <math.h>

// QANetAttBlock: B=16, S=1024, HID=512, H=8, DK=64
constexpr int CB = 16;
constexpr int CS = 1024;
constexpr int CHID = 512;
constexpr int CH = 8;
constexpr int CDK = 64;

typedef _Float16 f16;
typedef __attribute__((ext_vector_type(8))) _Float16 f16x8;
typedef __attribute__((ext_vector_type(4))) _Float16 f16x4;
typedef __attribute__((ext_vector_type(4))) float f32x4;

__device__ inline f32x4 mfma16(f16x8 a, f16x8 b, f32x4 c) {
  return __builtin_amdgcn_mfma_f32_16x16x32_f16(a, b, c, 0, 0, 0);
}

// log2(e): folded into Q prescale so softmax uses exp2 directly
#define LOG2E 1.4426950408889634f

// ---------------------------------------------------------------------------
// prep: blocks 0..8191 cast x fp32->fp16; blocks 8192..8207 compute lens[b]
// and zero Vsum (ws is poisoned 0xAA).
// ---------------------------------------------------------------------------
__global__ __launch_bounds__(256) void prep_kernel(const float4* __restrict__ x,
                                                   f16x4* __restrict__ xh,
                                                   const int* __restrict__ mask,
                                                   int* __restrict__ lens,
                                                   float* __restrict__ Vsum) {
  const int bid = blockIdx.x, t = threadIdx.x;
  __shared__ int red[256];
  if (bid < 8192) {
    const int idx = bid * 256 + t;
    const float4 v = x[idx];
    f16x4 o;
    o[0] = (f16)v.x; o[1] = (f16)v.y; o[2] = (f16)v.z; o[3] = (f16)v.w;
    xh[idx] = o;
  } else {
    const int b = bid - 8192;
    const int g = b * 256 + t;
    Vsum[g * 2] = 0.f;
    Vsum[g * 2 + 1] = 0.f;
    int s = 0;
    for (int i = t; i < CS; i += 256) s += mask[b * CS + i];
    red[t] = s;
    __syncthreads();
    for (int off = 128; off > 0; off >>= 1) {
      if (t < off) red[t] += red[t + off];
      __syncthreads();
    }
    if (t == 0) lens[b] = red[0];
  }
}

// ---------------------------------------------------------------------------
// cast + transpose weights via LDS (coalesced fp32 reads).
// ---------------------------------------------------------------------------
__global__ __launch_bounds__(256) void cast_w_kernel(const float* __restrict__ Wq,
                                                     const float* __restrict__ Wk,
                                                     const float* __restrict__ Wv,
                                                     const float* __restrict__ Wout,
                                                     f16* __restrict__ wtAll) {
  const int y = blockIdx.y, kb = blockIdx.x, t = threadIdx.x;
  const int k0 = kb * 64;
  const float* src;
  int ldsrc;
  f16* dst;
  if (y < 24) {
    const int which = y >> 3, h = y & 7;
    const float* W = (which == 0) ? Wq : (which == 1) ? Wk : Wv;
    src = W + (size_t)h * 32768 + (size_t)k0 * 64;
    ldsrc = 64;
    dst = wtAll + (size_t)which * 262144 + (size_t)h * 32768;
  } else {
    const int c = y - 24;
    src = Wout + (size_t)k0 * 512 + c * 64;
    ldsrc = 512;
    dst = wtAll + (size_t)3 * 262144 + (size_t)c * 64 * 512;
  }

  __shared__ float Ts[64][68];
  {
    const int kr = t >> 4, cg = (t & 15) * 4;
#pragma unroll
    for (int rr = 0; rr < 4; ++rr) {
      const float4 v = *(const float4*)&src[(size_t)(rr * 16 + kr) * ldsrc + cg];
      Ts[rr * 16 + kr][cg] = v.x;
      Ts[rr * 16 + kr][cg + 1] = v.y;
      Ts[rr * 16 + kr][cg + 2] = v.z;
      Ts[rr * 16 + kr][cg + 3] = v.w;
    }
  }
  __syncthreads();
  {
    const int n = t >> 2, seg = t & 3;
    f16x8 a, b;
#pragma unroll
    for (int j = 0; j < 8; ++j) {
      a[j] = (f16)Ts[seg * 16 + j][n];
      b[j] = (f16)Ts[seg * 16 + 8 + j][n];
    }
    f16* d = &dst[(size_t)n * 512 + k0 + seg * 16];
    *(f16x8*)d = a;
    *(f16x8*)(d + 8) = b;
  }
}

// ---------------------------------------------------------------------------
// Fused QKV projection: 128x128-tile GEMM vs Wcat[512,1536], reg-prefetch.
// grid (12 col-tiles, 128 row-tiles): consecutive blocks share the x-tile.
// Q pre-scaled by log2e/sqrt(n[b]). ALL epilogues route through the LDS
// union for coalesced 128-B-run stores. V also: fp32 column sums -> Vsum.
// ---------------------------------------------------------------------------
__global__ __launch_bounds__(256) void qkvf_kernel(
    const f16* __restrict__ xh, const f16* __restrict__ wtAll,
    const int* __restrict__ lens, f16* __restrict__ Qh, f16* __restrict__ Kh,
    f16* __restrict__ Vth, float* __restrict__ Vsum) {
  const int ct = blockIdx.x, rt = blockIdx.y;
  const int which = ct >> 2, hp = ct & 3;
  const f16* Wt = wtAll + (size_t)which * 262144 + (size_t)hp * 65536;
  const int row0 = rt * 128;
  const int b = row0 >> 10, s0 = row0 & 1023;
  const int h0 = hp * 2;
  const int t = threadIdx.x;
  const int w = t >> 6, lane = t & 63, quad = lane >> 4, lcol = lane & 15;
  const int wr = w >> 1, wc = w & 1;

  __shared__ union SM {
    struct { f16 Xs[128][40]; f16 Ws[128][40]; } a;
    f16 Ts[128][136];  // epilogue staging
  } sm;

  f32x4 acc[4][4];
#pragma unroll
  for (int i = 0; i < 4; ++i)
#pragma unroll
    for (int j = 0; j < 4; ++j) acc[i][j] = (f32x4){0.f, 0.f, 0.f, 0.f};

  f16x8 px[2], pw[2];
#pragma unroll
  for (int i = 0; i < 2; ++i) {
    const int c = t + 256 * i, r = c >> 2, sg = c & 3;
    px[i] = *(const f16x8*)&xh[(size_t)(row0 + r) * CHID + sg * 8];
    pw[i] = *(const f16x8*)&Wt[(size_t)r * CHID + sg * 8];
  }

  for (int k0 = 0; k0 < CHID; k0 += 32) {
    __syncthreads();
#pragma unroll
    for (int i = 0; i < 2; ++i) {
      const int c = t + 256 * i, r = c >> 2, sg = c & 3;
      *(f16x8*)&sm.a.Xs[r][sg * 8] = px[i];
      *(f16x8*)&sm.a.Ws[r][sg * 8] = pw[i];
    }
    __syncthreads();
    const int kn = (k0 + 32 < CHID) ? k0 + 32 : k0;
#pragma unroll
    for (int i = 0; i < 2; ++i) {
      const int c = t + 256 * i, r = c >> 2, sg = c & 3;
      px[i] = *(const f16x8*)&xh[(size_t)(row0 + r) * CHID + kn + sg * 8];
      pw[i] = *(const f16x8*)&Wt[(size_t)r * CHID + kn + sg * 8];
    }
    f16x8 af[4], bf[4];
#pragma unroll
    for (int i = 0; i < 4; ++i)
      af[i] = *(const f16x8*)&sm.a.Xs[wr * 64 + i * 16 + lcol][quad * 8];
#pragma unroll
    for (int j = 0; j < 4; ++j)
      bf[j] = *(const f16x8*)&sm.a.Ws[wc * 64 + j * 16 + lcol][quad * 8];
#pragma unroll
    for (int i = 0; i < 4; ++i)
#pragma unroll
      for (int j = 0; j < 4; ++j) acc[i][j] = mfma16(af[i], bf[j], acc[i][j]);
  }

  if (which == 2) {
    // fp32 column sums -> Vsum (quad-reduced, register-only)
#pragma unroll
    for (int j = 0; j < 4; ++j) {
      float ps = 0.f;
#pragma unroll
      for (int i = 0; i < 4; ++i)
#pragma unroll
        for (int rr = 0; rr < 4; ++rr) ps += acc[i][j][rr];
      ps += __shfl_xor(ps, 16);
      ps += __shfl_xor(ps, 32);
      if (quad == 0) {
        const int d128 = wc * 64 + j * 16 + lcol;
        const int h = h0 + (d128 >> 6), d = d128 & 63;
        atomicAdd(&Vsum[((size_t)b * CH + h) * CDK + d], ps);
      }
    }
    // Ts[n][s]: packed f16x4 transpose writes, then coalesced V^T stores
    __syncthreads();
#pragma unroll
    for (int i = 0; i < 4; ++i)
#pragma unroll
      for (int j = 0; j < 4; ++j) {
        f16x4 v4;
#pragma unroll
        for (int rr = 0; rr < 4; ++rr) v4[rr] = (f16)acc[i][j][rr];
        *(f16x4*)&sm.Ts[wc * 64 + j * 16 + lcol][wr * 64 + i * 16 + quad * 4] =
            v4;
      }
    __syncthreads();
    const int c16 = t & 15;
#pragma unroll
    for (int p = 0; p < 8; ++p) {
      const int vr = p * 16 + (t >> 4);
      const int h = h0 + (vr >> 6), d = vr & 63;
      *(f16x8*)&Vth[(((size_t)b * CH + h) * CDK + d) * CS + s0 + c16 * 8] =
          *(const f16x8*)&sm.Ts[vr][c16 * 8];
    }
  } else {
    // Ts[s][n], then coalesced [B,H,S,64] stores (128-B runs)
    const float qsc =
        (which == 0) ? rsqrtf((float)lens[b]) * LOG2E : 1.0f;
    __syncthreads();
#pragma unroll
    for (int i = 0; i < 4; ++i)
#pragma unroll
      for (int j = 0; j < 4; ++j)
#pragma unroll
        for (int rr = 0; rr < 4; ++rr)
          sm.Ts[wr * 64 + i * 16 + quad * 4 + rr][wc * 64 + j * 16 + lcol] =
              (f16)(acc[i][j][rr] * qsc);
    __syncthreads();
    f16* O = (which == 0) ? Qh : Kh;
    const int c8 = t & 7;
#pragma unroll
    for (int p = 0; p < 4; ++p) {
      const int row = p * 32 + (t >> 3);
#pragma unroll
      for (int half = 0; half < 2; ++half) {
        const int h = h0 + half;
        *(f16x8*)&O[(((size_t)b * CH + h) * CS + s0 + row) * CDK + c8 * 8] =
            *(const f16x8*)&sm.Ts[row][half * 64 + c8 * 8];
      }
    }
  }
}

// ---------------------------------------------------------------------------
// Attention (MFMA flash; Q pre-scaled w/ log2e; exp2 softmax; reg-prefetch).
// Fully-invalid q-tiles (qt*128 >= n) early-exit with Vsum/1024.
// grid (8 q-tiles, 8 heads, 16 batch), block 256 = 4 waves x 32 q-rows.
// ---------------------------------------------------------------------------
__global__ __launch_bounds__(256) void attn_kernel(
    const f16* __restrict__ Qh, const f16* __restrict__ Kh,
    const f16* __restrict__ Vth, const int* __restrict__ lens,
    const float* __restrict__ Vsum, f16* __restrict__ Hbh) {
  const int qt = blockIdx.x, h = blockIdx.y, b = blockIdx.z;
  const int n = lens[b];
  const int t = threadIdx.x, w = t >> 6, lane = t & 63, quad = lane >> 4,
            lcol = lane & 15;

  const size_t bh = ((size_t)b * CH + h) * CS;
  const size_t bhd = ((size_t)b * CH + h) * CDK;

  // fully-invalid q-tile: uniform mean of V over all S, skip everything
  if (qt * 128 >= n) {
    const int lr = lane >> 3, lc = lane & 7;
    f16x8 mv;
#pragma unroll
    for (int j = 0; j < 8; ++j)
      mv[j] = (f16)(Vsum[bhd + lc * 8 + j] * (1.0f / 1024.0f));
#pragma unroll
    for (int p = 0; p < 4; ++p) {
      const int srow = qt * 128 + w * 32 + p * 8 + lr;
      *(f16x8*)&Hbh[((size_t)b * CS + srow) * (CH * CDK) + h * CDK + lc * 8] =
          mv;
    }
    return;
  }

  const int nt = (n + 63) >> 6;

  __shared__ f16 Ks[64][72];     // [k][d]
  __shared__ f16 Vs[64][72];     // V^T: [d][k]
  __shared__ f16 Pt[4][32][72];  // wave-private P / O staging

  const int qbase = qt * 128 + w * 32;
  f16x8 qa[2][2];
#pragma unroll
  for (int set = 0; set < 2; ++set) {
    const size_t qr = bh + qbase + set * 16 + lcol;
    qa[set][0] = *(const f16x8*)&Qh[qr * CDK + quad * 8];
    qa[set][1] = *(const f16x8*)&Qh[qr * CDK + 32 + quad * 8];
  }

  f32x4 o[2][4];
#pragma unroll
  for (int set = 0; set < 2; ++set)
#pragma unroll
    for (int dt = 0; dt < 4; ++dt) o[set][dt] = (f32x4){0.f, 0.f, 0.f, 0.f};
  float lp[2][4] = {{0.f, 0.f, 0.f, 0.f}, {0.f, 0.f, 0.f, 0.f}};

  f16x8 pk[2], pv[2];
#pragma unroll
  for (int i = 0; i < 2; ++i) {
    const int c = t + 256 * i, r = c >> 3, sg = c & 7;
    pk[i] = *(const f16x8*)&Kh[(bh + r) * CDK + sg * 8];
    pv[i] = *(const f16x8*)&Vth[(bhd + r) * CS + sg * 8];
  }

  for (int kt = 0; kt < nt; ++kt) {
    __syncthreads();
#pragma unroll
    for (int i = 0; i < 2; ++i) {
      const int c = t + 256 * i, r = c >> 3, sg = c & 7;
      *(f16x8*)&Ks[r][sg * 8] = pk[i];
      *(f16x8*)&Vs[r][sg * 8] = pv[i];
    }
    __syncthreads();
    const int ktn = (kt + 1 < nt) ? kt + 1 : kt;
#pragma unroll
    for (int i = 0; i < 2; ++i) {
      const int c = t + 256 * i, r = c >> 3, sg = c & 7;
      pk[i] = *(const f16x8*)&Kh[(bh + ktn * 64 + r) * CDK + sg * 8];
      pv[i] = *(const f16x8*)&Vth[(bhd + r) * CS + ktn * 64 + sg * 8];
    }

    // K B-frags hoisted: shared by both q-row sets
    f16x8 kb[4][2];
#pragma unroll
    for (int ct = 0; ct < 4; ++ct) {
      kb[ct][0] = *(const f16x8*)&Ks[ct * 16 + lcol][quad * 8];
      kb[ct][1] = *(const f16x8*)&Ks[ct * 16 + lcol][32 + quad * 8];
    }

#pragma unroll
    for (int set = 0; set < 2; ++set) {
      f32x4 st[4];
#pragma unroll
      for (int ct = 0; ct < 4; ++ct) {
        st[ct] = mfma16(qa[set][0], kb[ct][0], (f32x4){0.f, 0.f, 0.f, 0.f});
        st[ct] = mfma16(qa[set][1], kb[ct][1], st[ct]);
      }
#pragma unroll
      for (int ct = 0; ct < 4; ++ct) {
        const bool kvld = (kt * 64 + ct * 16 + lcol) < n;
#pragma unroll
        for (int r = 0; r < 4; ++r) {
          float p = exp2f(st[ct][r]);
          p = kvld ? p : 0.f;
          lp[set][r] += p;
          Pt[w][set * 16 + quad * 4 + r][ct * 16 + lcol] = (f16)p;
        }
      }
    }

    f16x8 pa[2][2];
#pragma unroll
    for (int set = 0; set < 2; ++set) {
      pa[set][0] = *(const f16x8*)&Pt[w][set * 16 + lcol][quad * 8];
      pa[set][1] = *(const f16x8*)&Pt[w][set * 16 + lcol][32 + quad * 8];
    }

#pragma unroll
    for (int dt = 0; dt < 4; ++dt) {
      const f16x8 vb0 = *(const f16x8*)&Vs[dt * 16 + lcol][quad * 8];
      const f16x8 vb1 = *(const f16x8*)&Vs[dt * 16 + lcol][32 + quad * 8];
#pragma unroll
      for (int set = 0; set < 2; ++set) {
        o[set][dt] = mfma16(pa[set][0], vb0, o[set][dt]);
        o[set][dt] = mfma16(pa[set][1], vb1, o[set][dt]);
      }
    }
  }

  float invl[2][4];
#pragma unroll
  for (int set = 0; set < 2; ++set)
#pragma unroll
    for (int r = 0; r < 4; ++r) {
      float v = lp[set][r];
      v += __shfl_xor(v, 1);
      v += __shfl_xor(v, 2);
      v += __shfl_xor(v, 4);
      v += __shfl_xor(v, 8);
      invl[set][r] = 1.0f / v;
    }

  // O -> wave-private Pt (f16), then coalesced 128-B-run stores
#pragma unroll
  for (int set = 0; set < 2; ++set)
#pragma unroll
    for (int dt = 0; dt < 4; ++dt)
#pragma unroll
      for (int r = 0; r < 4; ++r) {
        const int srow_l = set * 16 + quad * 4 + r;
        const int d = dt * 16 + lcol;
        const float val = (qbase + srow_l < n)
                              ? o[set][dt][r] * invl[set][r]
                              : Vsum[bhd + d] * (1.0f / 1024.0f);
        Pt[w][srow_l][d] = (f16)val;
      }
  {
    const int lr = lane >> 3, lc = lane & 7;
#pragma unroll
    for (int p = 0; p < 4; ++p) {
      const int row = p * 8 + lr;
      *(f16x8*)&Hbh[((size_t)b * CS + qbase + row) * (CH * CDK) + h * CDK +
                    lc * 8] = *(const f16x8*)&Pt[w][row][lc * 8];
    }
  }
}

// ---------------------------------------------------------------------------
// Output projection: out[16384,512] = Hbh @ Wout, 128x128 tiles, reg-prefetch.
// ---------------------------------------------------------------------------
__global__ __launch_bounds__(256) void outp_kernel(const f16* __restrict__ Hbh,
                                                   const f16* __restrict__ woutt,
                                                   float* __restrict__ out) {
  const int rt = blockIdx.x, ctile = blockIdx.y;
  const int row0 = rt * 128, col0 = ctile * 128;
  const f16* Wt = woutt + (size_t)col0 * CHID;
  const int t = threadIdx.x;
  const int w = t >> 6, lane = t & 63, quad = lane >> 4, lcol = lane & 15;
  const int wr = w >> 1, wc = w & 1;

  __shared__ f16 Hs[128][40];
  __shared__ f16 Ws[128][40];

  f32x4 acc[4][4];
#pragma unroll
  for (int i = 0; i < 4; ++i)
#pragma unroll
    for (int j = 0; j < 4; ++j) acc[i][j] = (f32x4){0.f, 0.f, 0.f, 0.f};

  f16x8 ph[2], pw[2];
#pragma unroll
  for (int i = 0; i < 2; ++i) {
    const int c = t + 256 * i, r = c >> 2, sg = c & 3;
    ph[i] = *(const f16x8*)&Hbh[(size_t)(row0 + r) * CHID + sg * 8];
    pw[i] = *(const f16x8*)&Wt[(size_t)r * CHID + sg * 8];
  }

  for (int k0 = 0; k0 < CHID; k0 += 32) {
    __syncthreads();
#pragma unroll
    for (int i = 0; i < 2; ++i) {
      const int c = t + 256 * i, r = c >> 2, sg = c & 3;
      *(f16x8*)&Hs[r][sg * 8] = ph[i];
      *(f16x8*)&Ws[r][sg * 8] = pw[i];
    }
    __syncthreads();
    const int kn = (k0 + 32 < CHID) ? k0 + 32 : k0;
#pragma unroll
    for (int i = 0; i < 2; ++i) {
      const int c = t + 256 * i, r = c >> 2, sg = c & 3;
      ph[i] = *(const f16x8*)&Hbh[(size_t)(row0 + r) * CHID + kn + sg * 8];
      pw[i] = *(const f16x8*)&Wt[(size_t)r * CHID + kn + sg * 8];
    }
    f16x8 af[4], bf[4];
#pragma unroll
    for (int i = 0; i < 4; ++i)
      af[i] = *(const f16x8*)&Hs[wr * 64 + i * 16 + lcol][quad * 8];
#pragma unroll
    for (int j = 0; j < 4; ++j)
      bf[j] = *(const f16x8*)&Ws[wc * 64 + j * 16 + lcol][quad * 8];
#pragma unroll
    for (int i = 0; i < 4; ++i)
#pragma unroll
      for (int j = 0; j < 4; ++j) acc[i][j] = mfma16(af[i], bf[j], acc[i][j]);
  }

#pragma unroll
  for (int i = 0; i < 4; ++i) {
#pragma unroll
    for (int rr = 0; rr < 4; ++rr) {
      const size_t rg = row0 + wr * 64 + i * 16 + quad * 4 + rr;
#pragma unroll
      for (int j = 0; j < 4; ++j)
        out[rg * CHID + col0 + wc * 64 + j * 16 + lcol] = acc[i][j][rr];
    }
  }
}

// ---------------------------------------------------------------------------
extern "C" void kernel_launch(void* const* d_in, const int* in_sizes, int n_in,
                              void* d_out, int out_size, void* d_ws,
                              size_t ws_size, hipStream_t stream) {
  const float* x = (const float*)d_in[0];
  const int* mask = (const int*)d_in[1];
  const float* Wq = (const float*)d_in[2];
  const float* Wk = (const float*)d_in[3];
  const float* Wv = (const float*)d_in[4];
  const float* Wout = (const float*)d_in[5];
  float* out = (float*)d_out;

  char* ws = (char*)d_ws;
  int* lens = (int*)ws;
  size_t off = 1024;
  const size_t NX = (size_t)CB * CS * CHID;   // 8,388,608
  const size_t NW = (size_t)CH * CHID * CDK;  // 262,144 per weight
  f16* xh = (f16*)(ws + off);    off += NX * 2;
  f16* wtAll = (f16*)(ws + off); off += NW * 4 * 2;
  f16* Qh = (f16*)(ws + off);    off += NX * 2;
  f16* Kh = (f16*)(ws + off);    off += NX * 2;
  f16* Vth = (f16*)(ws + off);   off += NX * 2;
  f16* Hbh = (f16*)(ws + off);   off += NX * 2;
  float* Vsum = (float*)(ws + off); off += (size_t)CB * CH * CDK * 4;
  f16* woutt = wtAll + NW * 3;

  prep_kernel<<<8208, 256, 0, stream>>>((const float4*)x, (f16x4*)xh, mask,
                                        lens, Vsum);
  cast_w_kernel<<<dim3(8, 32), 256, 0, stream>>>(Wq, Wk, Wv, Wout, wtAll);
  qkvf_kernel<<<dim3(12, 128), 256, 0, stream>>>(xh, wtAll, lens, Qh, Kh, Vth,
                                                 Vsum);
  attn_kernel<<<dim3(CS / 128, CH, CB), 256, 0, stream>>>(Qh, Kh, Vth, lens,
                                                          Vsum, Hbh);
  outp_kernel<<<dim3(128, 4), 256, 0, stream>>>(Hbh, woutt, out);
}

// Round 9
// 225.197 us; speedup vs baseline: 1.0049x; 1.0049x over previous
//
#include <hip/hip_runtime.h>
#include <math.h>

// QANetAttBlock: B=16, S=1024, HID=512, H=8, DK=64
constexpr int CB = 16;
constexpr int CS = 1024;
constexpr int CHID = 512;
constexpr int CH = 8;
constexpr int CDK = 64;

typedef _Float16 f16;
typedef __attribute__((ext_vector_type(8))) _Float16 f16x8;
typedef __attribute__((ext_vector_type(4))) _Float16 f16x4;
typedef __attribute__((ext_vector_type(4))) float f32x4;

__device__ inline f32x4 mfma16(f16x8 a, f16x8 b, f32x4 c) {
  return __builtin_amdgcn_mfma_f32_16x16x32_f16(a, b, c, 0, 0, 0);
}

// log2(e): folded into Q prescale so softmax uses exp2 directly
#define LOG2E 1.4426950408889634f

// ---------------------------------------------------------------------------
// prep: blocks 0..8191 cast x fp32->fp16; blocks 8192..8207 compute lens[b]
// and zero Vsum (ws is poisoned 0xAA).
// ---------------------------------------------------------------------------
__global__ __launch_bounds__(256) void prep_kernel(const float4* __restrict__ x,
                                                   f16x4* __restrict__ xh,
                                                   const int* __restrict__ mask,
                                                   int* __restrict__ lens,
                                                   float* __restrict__ Vsum) {
  const int bid = blockIdx.x, t = threadIdx.x;
  __shared__ int red[256];
  if (bid < 8192) {
    const int idx = bid * 256 + t;
    const float4 v = x[idx];
    f16x4 o;
    o[0] = (f16)v.x; o[1] = (f16)v.y; o[2] = (f16)v.z; o[3] = (f16)v.w;
    xh[idx] = o;
  } else {
    const int b = bid - 8192;
    const int g = b * 256 + t;
    Vsum[g * 2] = 0.f;
    Vsum[g * 2 + 1] = 0.f;
    int s = 0;
    for (int i = t; i < CS; i += 256) s += mask[b * CS + i];
    red[t] = s;
    __syncthreads();
    for (int off = 128; off > 0; off >>= 1) {
      if (t < off) red[t] += red[t + off];
      __syncthreads();
    }
    if (t == 0) lens[b] = red[0];
  }
}

// ---------------------------------------------------------------------------
// cast + transpose weights via LDS (coalesced fp32 reads).
// ---------------------------------------------------------------------------
__global__ __launch_bounds__(256) void cast_w_kernel(const float* __restrict__ Wq,
                                                     const float* __restrict__ Wk,
                                                     const float* __restrict__ Wv,
                                                     const float* __restrict__ Wout,
                                                     f16* __restrict__ wtAll) {
  const int y = blockIdx.y, kb = blockIdx.x, t = threadIdx.x;
  const int k0 = kb * 64;
  const float* src;
  int ldsrc;
  f16* dst;
  if (y < 24) {
    const int which = y >> 3, h = y & 7;
    const float* W = (which == 0) ? Wq : (which == 1) ? Wk : Wv;
    src = W + (size_t)h * 32768 + (size_t)k0 * 64;
    ldsrc = 64;
    dst = wtAll + (size_t)which * 262144 + (size_t)h * 32768;
  } else {
    const int c = y - 24;
    src = Wout + (size_t)k0 * 512 + c * 64;
    ldsrc = 512;
    dst = wtAll + (size_t)3 * 262144 + (size_t)c * 64 * 512;
  }

  __shared__ float Ts[64][68];
  {
    const int kr = t >> 4, cg = (t & 15) * 4;
#pragma unroll
    for (int rr = 0; rr < 4; ++rr) {
      const float4 v = *(const float4*)&src[(size_t)(rr * 16 + kr) * ldsrc + cg];
      Ts[rr * 16 + kr][cg] = v.x;
      Ts[rr * 16 + kr][cg + 1] = v.y;
      Ts[rr * 16 + kr][cg + 2] = v.z;
      Ts[rr * 16 + kr][cg + 3] = v.w;
    }
  }
  __syncthreads();
  {
    const int n = t >> 2, seg = t & 3;
    f16x8 a, b;
#pragma unroll
    for (int j = 0; j < 8; ++j) {
      a[j] = (f16)Ts[seg * 16 + j][n];
      b[j] = (f16)Ts[seg * 16 + 8 + j][n];
    }
    f16* d = &dst[(size_t)n * 512 + k0 + seg * 16];
    *(f16x8*)d = a;
    *(f16x8*)(d + 8) = b;
  }
}

// ---------------------------------------------------------------------------
// Fused QKV projection: 128x128-tile GEMM vs Wcat[512,1536], reg-prefetch.
// grid (12 col-tiles, 128 row-tiles): consecutive blocks share the x-tile.
// Q pre-scaled by log2e/sqrt(n[b]). ALL epilogues route through the LDS
// union for coalesced 128-B-run stores. V also: fp32 column sums -> Vsum.
// ---------------------------------------------------------------------------
__global__ __launch_bounds__(256) void qkvf_kernel(
    const f16* __restrict__ xh, const f16* __restrict__ wtAll,
    const int* __restrict__ lens, f16* __restrict__ Qh, f16* __restrict__ Kh,
    f16* __restrict__ Vth, float* __restrict__ Vsum) {
  const int ct = blockIdx.x, rt = blockIdx.y;
  const int which = ct >> 2, hp = ct & 3;
  const f16* Wt = wtAll + (size_t)which * 262144 + (size_t)hp * 65536;
  const int row0 = rt * 128;
  const int b = row0 >> 10, s0 = row0 & 1023;
  const int h0 = hp * 2;
  const int t = threadIdx.x;
  const int w = t >> 6, lane = t & 63, quad = lane >> 4, lcol = lane & 15;
  const int wr = w >> 1, wc = w & 1;

  __shared__ union SM {
    struct { f16 Xs[128][40]; f16 Ws[128][40]; } a;
    f16 Ts[128][136];  // epilogue staging
  } sm;

  f32x4 acc[4][4];
#pragma unroll
  for (int i = 0; i < 4; ++i)
#pragma unroll
    for (int j = 0; j < 4; ++j) acc[i][j] = (f32x4){0.f, 0.f, 0.f, 0.f};

  f16x8 px[2], pw[2];
#pragma unroll
  for (int i = 0; i < 2; ++i) {
    const int c = t + 256 * i, r = c >> 2, sg = c & 3;
    px[i] = *(const f16x8*)&xh[(size_t)(row0 + r) * CHID + sg * 8];
    pw[i] = *(const f16x8*)&Wt[(size_t)r * CHID + sg * 8];
  }

  for (int k0 = 0; k0 < CHID; k0 += 32) {
    __syncthreads();
#pragma unroll
    for (int i = 0; i < 2; ++i) {
      const int c = t + 256 * i, r = c >> 2, sg = c & 3;
      *(f16x8*)&sm.a.Xs[r][sg * 8] = px[i];
      *(f16x8*)&sm.a.Ws[r][sg * 8] = pw[i];
    }
    __syncthreads();
    const int kn = (k0 + 32 < CHID) ? k0 + 32 : k0;
#pragma unroll
    for (int i = 0; i < 2; ++i) {
      const int c = t + 256 * i, r = c >> 2, sg = c & 3;
      px[i] = *(const f16x8*)&xh[(size_t)(row0 + r) * CHID + kn + sg * 8];
      pw[i] = *(const f16x8*)&Wt[(size_t)r * CHID + kn + sg * 8];
    }
    f16x8 af[4], bf[4];
#pragma unroll
    for (int i = 0; i < 4; ++i)
      af[i] = *(const f16x8*)&sm.a.Xs[wr * 64 + i * 16 + lcol][quad * 8];
#pragma unroll
    for (int j = 0; j < 4; ++j)
      bf[j] = *(const f16x8*)&sm.a.Ws[wc * 64 + j * 16 + lcol][quad * 8];
#pragma unroll
    for (int i = 0; i < 4; ++i)
#pragma unroll
      for (int j = 0; j < 4; ++j) acc[i][j] = mfma16(af[i], bf[j], acc[i][j]);
  }

  if (which == 2) {
    // fp32 column sums -> Vsum (quad-reduced, register-only)
#pragma unroll
    for (int j = 0; j < 4; ++j) {
      float ps = 0.f;
#pragma unroll
      for (int i = 0; i < 4; ++i)
#pragma unroll
        for (int rr = 0; rr < 4; ++rr) ps += acc[i][j][rr];
      ps += __shfl_xor(ps, 16);
      ps += __shfl_xor(ps, 32);
      if (quad == 0) {
        const int d128 = wc * 64 + j * 16 + lcol;
        const int h = h0 + (d128 >> 6), d = d128 & 63;
        atomicAdd(&Vsum[((size_t)b * CH + h) * CDK + d], ps);
      }
    }
    // Ts[n][s]: packed f16x4 transpose writes, then coalesced V^T stores
    __syncthreads();
#pragma unroll
    for (int i = 0; i < 4; ++i)
#pragma unroll
      for (int j = 0; j < 4; ++j) {
        f16x4 v4;
#pragma unroll
        for (int rr = 0; rr < 4; ++rr) v4[rr] = (f16)acc[i][j][rr];
        *(f16x4*)&sm.Ts[wc * 64 + j * 16 + lcol][wr * 64 + i * 16 + quad * 4] =
            v4;
      }
    __syncthreads();
    const int c16 = t & 15;
#pragma unroll
    for (int p = 0; p < 8; ++p) {
      const int vr = p * 16 + (t >> 4);
      const int h = h0 + (vr >> 6), d = vr & 63;
      *(f16x8*)&Vth[(((size_t)b * CH + h) * CDK + d) * CS + s0 + c16 * 8] =
          *(const f16x8*)&sm.Ts[vr][c16 * 8];
    }
  } else {
    // Ts[s][n], then coalesced [B,H,S,64] stores (128-B runs)
    const float qsc =
        (which == 0) ? rsqrtf((float)lens[b]) * LOG2E : 1.0f;
    __syncthreads();
#pragma unroll
    for (int i = 0; i < 4; ++i)
#pragma unroll
      for (int j = 0; j < 4; ++j)
#pragma unroll
        for (int rr = 0; rr < 4; ++rr)
          sm.Ts[wr * 64 + i * 16 + quad * 4 + rr][wc * 64 + j * 16 + lcol] =
              (f16)(acc[i][j][rr] * qsc);
    __syncthreads();
    f16* O = (which == 0) ? Qh : Kh;
    const int c8 = t & 7;
#pragma unroll
    for (int p = 0; p < 4; ++p) {
      const int row = p * 32 + (t >> 3);
#pragma unroll
      for (int half = 0; half < 2; ++half) {
        const int h = h0 + half;
        *(f16x8*)&O[(((size_t)b * CH + h) * CS + s0 + row) * CDK + c8 * 8] =
            *(const f16x8*)&sm.Ts[row][half * 64 + c8 * 8];
      }
    }
  }
}

// ---------------------------------------------------------------------------
// Attention (MFMA flash; Q pre-scaled w/ log2e; exp2 softmax; reg-prefetch).
// Fully-invalid q-tiles (qt*128 >= n) early-exit with Vsum/1024.
// K B-frags NOT hoisted (round-8 lesson: 32 extra live VGPRs halved
// occupancy, -28% perf; LDS re-reads at <=2-way conflict are nearly free).
// grid (8 q-tiles, 8 heads, 16 batch), block 256 = 4 waves x 32 q-rows.
// ---------------------------------------------------------------------------
__global__ __launch_bounds__(256) void attn_kernel(
    const f16* __restrict__ Qh, const f16* __restrict__ Kh,
    const f16* __restrict__ Vth, const int* __restrict__ lens,
    const float* __restrict__ Vsum, f16* __restrict__ Hbh) {
  const int qt = blockIdx.x, h = blockIdx.y, b = blockIdx.z;
  const int n = lens[b];
  const int t = threadIdx.x, w = t >> 6, lane = t & 63, quad = lane >> 4,
            lcol = lane & 15;

  const size_t bh = ((size_t)b * CH + h) * CS;
  const size_t bhd = ((size_t)b * CH + h) * CDK;

  // fully-invalid q-tile: uniform mean of V over all S, skip everything
  if (qt * 128 >= n) {
    const int lr = lane >> 3, lc = lane & 7;
    f16x8 mv;
#pragma unroll
    for (int j = 0; j < 8; ++j)
      mv[j] = (f16)(Vsum[bhd + lc * 8 + j] * (1.0f / 1024.0f));
#pragma unroll
    for (int p = 0; p < 4; ++p) {
      const int srow = qt * 128 + w * 32 + p * 8 + lr;
      *(f16x8*)&Hbh[((size_t)b * CS + srow) * (CH * CDK) + h * CDK + lc * 8] =
          mv;
    }
    return;
  }

  const int nt = (n + 63) >> 6;

  __shared__ f16 Ks[64][72];     // [k][d]
  __shared__ f16 Vs[64][72];     // V^T: [d][k]
  __shared__ f16 Pt[4][32][72];  // wave-private P / O staging

  const int qbase = qt * 128 + w * 32;
  f16x8 qa[2][2];
#pragma unroll
  for (int set = 0; set < 2; ++set) {
    const size_t qr = bh + qbase + set * 16 + lcol;
    qa[set][0] = *(const f16x8*)&Qh[qr * CDK + quad * 8];
    qa[set][1] = *(const f16x8*)&Qh[qr * CDK + 32 + quad * 8];
  }

  f32x4 o[2][4];
#pragma unroll
  for (int set = 0; set < 2; ++set)
#pragma unroll
    for (int dt = 0; dt < 4; ++dt) o[set][dt] = (f32x4){0.f, 0.f, 0.f, 0.f};
  float lp[2][4] = {{0.f, 0.f, 0.f, 0.f}, {0.f, 0.f, 0.f, 0.f}};

  f16x8 pk[2], pv[2];
#pragma unroll
  for (int i = 0; i < 2; ++i) {
    const int c = t + 256 * i, r = c >> 3, sg = c & 7;
    pk[i] = *(const f16x8*)&Kh[(bh + r) * CDK + sg * 8];
    pv[i] = *(const f16x8*)&Vth[(bhd + r) * CS + sg * 8];
  }

  for (int kt = 0; kt < nt; ++kt) {
    __syncthreads();
#pragma unroll
    for (int i = 0; i < 2; ++i) {
      const int c = t + 256 * i, r = c >> 3, sg = c & 7;
      *(f16x8*)&Ks[r][sg * 8] = pk[i];
      *(f16x8*)&Vs[r][sg * 8] = pv[i];
    }
    __syncthreads();
    const int ktn = (kt + 1 < nt) ? kt + 1 : kt;
#pragma unroll
    for (int i = 0; i < 2; ++i) {
      const int c = t + 256 * i, r = c >> 3, sg = c & 7;
      pk[i] = *(const f16x8*)&Kh[(bh + ktn * 64 + r) * CDK + sg * 8];
      pv[i] = *(const f16x8*)&Vth[(bhd + r) * CS + ktn * 64 + sg * 8];
    }

    // QK + exp, set-serial (kb loaded per set: short VGPR lifetime)
#pragma unroll
    for (int set = 0; set < 2; ++set) {
      f32x4 st[4];
#pragma unroll
      for (int ct = 0; ct < 4; ++ct) {
        const f16x8 kb0 = *(const f16x8*)&Ks[ct * 16 + lcol][quad * 8];
        const f16x8 kb1 = *(const f16x8*)&Ks[ct * 16 + lcol][32 + quad * 8];
        st[ct] = mfma16(qa[set][0], kb0, (f32x4){0.f, 0.f, 0.f, 0.f});
        st[ct] = mfma16(qa[set][1], kb1, st[ct]);
      }
#pragma unroll
      for (int ct = 0; ct < 4; ++ct) {
        const bool kvld = (kt * 64 + ct * 16 + lcol) < n;
#pragma unroll
        for (int r = 0; r < 4; ++r) {
          float p = exp2f(st[ct][r]);
          p = kvld ? p : 0.f;
          lp[set][r] += p;
          Pt[w][set * 16 + quad * 4 + r][ct * 16 + lcol] = (f16)p;
        }
      }
    }

    f16x8 pa[2][2];
#pragma unroll
    for (int set = 0; set < 2; ++set) {
      pa[set][0] = *(const f16x8*)&Pt[w][set * 16 + lcol][quad * 8];
      pa[set][1] = *(const f16x8*)&Pt[w][set * 16 + lcol][32 + quad * 8];
    }

#pragma unroll
    for (int dt = 0; dt < 4; ++dt) {
      const f16x8 vb0 = *(const f16x8*)&Vs[dt * 16 + lcol][quad * 8];
      const f16x8 vb1 = *(const f16x8*)&Vs[dt * 16 + lcol][32 + quad * 8];
#pragma unroll
      for (int set = 0; set < 2; ++set) {
        o[set][dt] = mfma16(pa[set][0], vb0, o[set][dt]);
        o[set][dt] = mfma16(pa[set][1], vb1, o[set][dt]);
      }
    }
  }

  float invl[2][4];
#pragma unroll
  for (int set = 0; set < 2; ++set)
#pragma unroll
    for (int r = 0; r < 4; ++r) {
      float v = lp[set][r];
      v += __shfl_xor(v, 1);
      v += __shfl_xor(v, 2);
      v += __shfl_xor(v, 4);
      v += __shfl_xor(v, 8);
      invl[set][r] = 1.0f / v;
    }

  // O -> wave-private Pt (f16), then coalesced 128-B-run stores
#pragma unroll
  for (int set = 0; set < 2; ++set)
#pragma unroll
    for (int dt = 0; dt < 4; ++dt)
#pragma unroll
      for (int r = 0; r < 4; ++r) {
        const int srow_l = set * 16 + quad * 4 + r;
        const int d = dt * 16 + lcol;
        const float val = (qbase + srow_l < n)
                              ? o[set][dt][r] * invl[set][r]
                              : Vsum[bhd + d] * (1.0f / 1024.0f);
        Pt[w][srow_l][d] = (f16)val;
      }
  {
    const int lr = lane >> 3, lc = lane & 7;
#pragma unroll
    for (int p = 0; p < 4; ++p) {
      const int row = p * 8 + lr;
      *(f16x8*)&Hbh[((size_t)b * CS + qbase + row) * (CH * CDK) + h * CDK +
                    lc * 8] = *(const f16x8*)&Pt[w][row][lc * 8];
    }
  }
}

// ---------------------------------------------------------------------------
// Output projection: out[16384,512] = Hbh @ Wout, 128x128 tiles, reg-prefetch.
// ---------------------------------------------------------------------------
__global__ __launch_bounds__(256) void outp_kernel(const f16* __restrict__ Hbh,
                                                   const f16* __restrict__ woutt,
                                                   float* __restrict__ out) {
  const int rt = blockIdx.x, ctile = blockIdx.y;
  const int row0 = rt * 128, col0 = ctile * 128;
  const f16* Wt = woutt + (size_t)col0 * CHID;
  const int t = threadIdx.x;
  const int w = t >> 6, lane = t & 63, quad = lane >> 4, lcol = lane & 15;
  const int wr = w >> 1, wc = w & 1;

  __shared__ f16 Hs[128][40];
  __shared__ f16 Ws[128][40];

  f32x4 acc[4][4];
#pragma unroll
  for (int i = 0; i < 4; ++i)
#pragma unroll
    for (int j = 0; j < 4; ++j) acc[i][j] = (f32x4){0.f, 0.f, 0.f, 0.f};

  f16x8 ph[2], pw[2];
#pragma unroll
  for (int i = 0; i < 2; ++i) {
    const int c = t + 256 * i, r = c >> 2, sg = c & 3;
    ph[i] = *(const f16x8*)&Hbh[(size_t)(row0 + r) * CHID + sg * 8];
    pw[i] = *(const f16x8*)&Wt[(size_t)r * CHID + sg * 8];
  }

  for (int k0 = 0; k0 < CHID; k0 += 32) {
    __syncthreads();
#pragma unroll
    for (int i = 0; i < 2; ++i) {
      const int c = t + 256 * i, r = c >> 2, sg = c & 3;
      *(f16x8*)&Hs[r][sg * 8] = ph[i];
      *(f16x8*)&Ws[r][sg * 8] = pw[i];
    }
    __syncthreads();
    const int kn = (k0 + 32 < CHID) ? k0 + 32 : k0;
#pragma unroll
    for (int i = 0; i < 2; ++i) {
      const int c = t + 256 * i, r = c >> 2, sg = c & 3;
      ph[i] = *(const f16x8*)&Hbh[(size_t)(row0 + r) * CHID + kn + sg * 8];
      pw[i] = *(const f16x8*)&Wt[(size_t)r * CHID + kn + sg * 8];
    }
    f16x8 af[4], bf[4];
#pragma unroll
    for (int i = 0; i < 4; ++i)
      af[i] = *(const f16x8*)&Hs[wr * 64 + i * 16 + lcol][quad * 8];
#pragma unroll
    for (int j = 0; j < 4; ++j)
      bf[j] = *(const f16x8*)&Ws[wc * 64 + j * 16 + lcol][quad * 8];
#pragma unroll
    for (int i = 0; i < 4; ++i)
#pragma unroll
      for (int j = 0; j < 4; ++j) acc[i][j] = mfma16(af[i], bf[j], acc[i][j]);
  }

#pragma unroll
  for (int i = 0; i < 4; ++i) {
#pragma unroll
    for (int rr = 0; rr < 4; ++rr) {
      const size_t rg = row0 + wr * 64 + i * 16 + quad * 4 + rr;
#pragma unroll
      for (int j = 0; j < 4; ++j)
        out[rg * CHID + col0 + wc * 64 + j * 16 + lcol] = acc[i][j][rr];
    }
  }
}

// ---------------------------------------------------------------------------
extern "C" void kernel_launch(void* const* d_in, const int* in_sizes, int n_in,
                              void* d_out, int out_size, void* d_ws,
                              size_t ws_size, hipStream_t stream) {
  const float* x = (const float*)d_in[0];
  const int* mask = (const int*)d_in[1];
  const float* Wq = (const float*)d_in[2];
  const float* Wk = (const float*)d_in[3];
  const float* Wv = (const float*)d_in[4];
  const float* Wout = (const float*)d_in[5];
  float* out = (float*)d_out;

  char* ws = (char*)d_ws;
  int* lens = (int*)ws;
  size_t off = 1024;
  const size_t NX = (size_t)CB * CS * CHID;   // 8,388,608
  const size_t NW = (size_t)CH * CHID * CDK;  // 262,144 per weight
  f16* xh = (f16*)(ws + off);    off += NX * 2;
  f16* wtAll = (f16*)(ws + off); off += NW * 4 * 2;
  f16* Qh = (f16*)(ws + off);    off += NX * 2;
  f16* Kh = (f16*)(ws + off);    off += NX * 2;
  f16* Vth = (f16*)(ws + off);   off += NX * 2;
  f16* Hbh = (f16*)(ws + off);   off += NX * 2;
  float* Vsum = (float*)(ws + off); off += (size_t)CB * CH * CDK * 4;
  f16* woutt = wtAll + NW * 3;

  prep_kernel<<<8208, 256, 0, stream>>>((const float4*)x, (f16x4*)xh, mask,
                                        lens, Vsum);
  cast_w_kernel<<<dim3(8, 32), 256, 0, stream>>>(Wq, Wk, Wv, Wout, wtAll);
  qkvf_kernel<<<dim3(12, 128), 256, 0, stream>>>(xh, wtAll, lens, Qh, Kh, Vth,
                                                 Vsum);
  attn_kernel<<<dim3(CS / 128, CH, CB), 256, 0, stream>>>(Qh, Kh, Vth, lens,
                                                          Vsum, Hbh);
  outp_kernel<<<dim3(128, 4), 256, 0, stream>>>(Hbh, woutt, out);
}

// Round 10
// 221.264 us; speedup vs baseline: 1.0228x; 1.0178x over previous
//
#include <hip/hip_runtime.h>
#include <math.h>

// QANetAttBlock: B=16, S=1024, HID=512, H=8, DK=64
constexpr int CB = 16;
constexpr int CS = 1024;
constexpr int CHID = 512;
constexpr int CH = 8;
constexpr int CDK = 64;

typedef _Float16 f16;
typedef __attribute__((ext_vector_type(8))) _Float16 f16x8;
typedef __attribute__((ext_vector_type(4))) _Float16 f16x4;
typedef __attribute__((ext_vector_type(4))) float f32x4;

__device__ inline f32x4 mfma16(f16x8 a, f16x8 b, f32x4 c) {
  return __builtin_amdgcn_mfma_f32_16x16x32_f16(a, b, c, 0, 0, 0);
}

// async global->LDS, 16B per lane; dest must be wave-uniform base + lane*16
__device__ inline void gld16(const void* g, void* l) {
  __builtin_amdgcn_global_load_lds(
      (const __attribute__((address_space(1))) void*)g,
      (__attribute__((address_space(3))) void*)l, 16, 0, 0);
}

#define LOG2E 1.4426950408889634f

// ---------------------------------------------------------------------------
// prep: blocks 0..8191 cast x fp32->fp16; blocks 8192..8207 compute lens[b]
// and zero Vsum (ws is poisoned 0xAA).
// ---------------------------------------------------------------------------
__global__ __launch_bounds__(256) void prep_kernel(const float4* __restrict__ x,
                                                   f16x4* __restrict__ xh,
                                                   const int* __restrict__ mask,
                                                   int* __restrict__ lens,
                                                   float* __restrict__ Vsum) {
  const int bid = blockIdx.x, t = threadIdx.x;
  __shared__ int red[256];
  if (bid < 8192) {
    const int idx = bid * 256 + t;
    const float4 v = x[idx];
    f16x4 o;
    o[0] = (f16)v.x; o[1] = (f16)v.y; o[2] = (f16)v.z; o[3] = (f16)v.w;
    xh[idx] = o;
  } else {
    const int b = bid - 8192;
    const int g = b * 256 + t;
    Vsum[g * 2] = 0.f;
    Vsum[g * 2 + 1] = 0.f;
    int s = 0;
    for (int i = t; i < CS; i += 256) s += mask[b * CS + i];
    red[t] = s;
    __syncthreads();
    for (int off = 128; off > 0; off >>= 1) {
      if (t < off) red[t] += red[t + off];
      __syncthreads();
    }
    if (t == 0) lens[b] = red[0];
  }
}

// ---------------------------------------------------------------------------
// cast + transpose weights via LDS (coalesced fp32 reads).
// ---------------------------------------------------------------------------
__global__ __launch_bounds__(256) void cast_w_kernel(const float* __restrict__ Wq,
                                                     const float* __restrict__ Wk,
                                                     const float* __restrict__ Wv,
                                                     const float* __restrict__ Wout,
                                                     f16* __restrict__ wtAll) {
  const int y = blockIdx.y, kb = blockIdx.x, t = threadIdx.x;
  const int k0 = kb * 64;
  const float* src;
  int ldsrc;
  f16* dst;
  if (y < 24) {
    const int which = y >> 3, h = y & 7;
    const float* W = (which == 0) ? Wq : (which == 1) ? Wk : Wv;
    src = W + (size_t)h * 32768 + (size_t)k0 * 64;
    ldsrc = 64;
    dst = wtAll + (size_t)which * 262144 + (size_t)h * 32768;
  } else {
    const int c = y - 24;
    src = Wout + (size_t)k0 * 512 + c * 64;
    ldsrc = 512;
    dst = wtAll + (size_t)3 * 262144 + (size_t)c * 64 * 512;
  }

  __shared__ float Ts[64][68];
  {
    const int kr = t >> 4, cg = (t & 15) * 4;
#pragma unroll
    for (int rr = 0; rr < 4; ++rr) {
      const float4 v = *(const float4*)&src[(size_t)(rr * 16 + kr) * ldsrc + cg];
      Ts[rr * 16 + kr][cg] = v.x;
      Ts[rr * 16 + kr][cg + 1] = v.y;
      Ts[rr * 16 + kr][cg + 2] = v.z;
      Ts[rr * 16 + kr][cg + 3] = v.w;
    }
  }
  __syncthreads();
  {
    const int n = t >> 2, seg = t & 3;
    f16x8 a, b;
#pragma unroll
    for (int j = 0; j < 8; ++j) {
      a[j] = (f16)Ts[seg * 16 + j][n];
      b[j] = (f16)Ts[seg * 16 + 8 + j][n];
    }
    f16* d = &dst[(size_t)n * 512 + k0 + seg * 16];
    *(f16x8*)d = a;
    *(f16x8*)(d + 8) = b;
  }
}

// ---------------------------------------------------------------------------
// Fused QKV projection: 128x128 tile, BK=64, global_load_lds width-16 staging
// into UNPADDED LDS (m97 structure). grid (12 col-tiles, 128 row-tiles).
// Q pre-scaled by log2e/sqrt(n[b]); epilogues via padded Ts union, coalesced.
// V: fp32 column sums -> Vsum (atomic).
// ---------------------------------------------------------------------------
__global__ __launch_bounds__(256) void qkvf_kernel(
    const f16* __restrict__ xh, const f16* __restrict__ wtAll,
    const int* __restrict__ lens, f16* __restrict__ Qh, f16* __restrict__ Kh,
    f16* __restrict__ Vth, float* __restrict__ Vsum) {
  const int ct = blockIdx.x, rt = blockIdx.y;
  const int which = ct >> 2, hp = ct & 3;
  const f16* Wt = wtAll + (size_t)which * 262144 + (size_t)hp * 65536;
  const int row0 = rt * 128;
  const int b = row0 >> 10, s0 = row0 & 1023;
  const int h0 = hp * 2;
  const int t = threadIdx.x;
  const int w = t >> 6, lane = t & 63, quad = lane >> 4, lcol = lane & 15;
  const int wr = w >> 1, wc = w & 1;

  __shared__ union SM {
    struct { f16 Xs[128][64]; f16 Ws[128][64]; } a;  // unpadded: lds-dma layout
    f16 Ts[128][136];                                // epilogue staging
  } sm;

  f32x4 acc[4][4];
#pragma unroll
  for (int i = 0; i < 4; ++i)
#pragma unroll
    for (int j = 0; j < 4; ++j) acc[i][j] = (f32x4){0.f, 0.f, 0.f, 0.f};

  for (int k0 = 0; k0 < CHID; k0 += 64) {
    __syncthreads();  // prior compute's LDS reads done
#pragma unroll
    for (int i = 0; i < 4; ++i) {
      const int c = t + 256 * i, r = c >> 3, sg = c & 7;
      gld16(&xh[(size_t)(row0 + r) * CHID + k0 + sg * 8],
            (char*)&sm.a.Xs[0][0] + c * 16);
      gld16(&Wt[(size_t)r * CHID + k0 + sg * 8],
            (char*)&sm.a.Ws[0][0] + c * 16);
    }
    __syncthreads();  // drains vmcnt: LDS tiles ready

    f16x8 bf0[4], bf1[4];
#pragma unroll
    for (int j = 0; j < 4; ++j) {
      bf0[j] = *(const f16x8*)&sm.a.Ws[wc * 64 + j * 16 + lcol][quad * 8];
      bf1[j] = *(const f16x8*)&sm.a.Ws[wc * 64 + j * 16 + lcol][32 + quad * 8];
    }
#pragma unroll
    for (int i = 0; i < 4; ++i) {
      const f16x8 af0 =
          *(const f16x8*)&sm.a.Xs[wr * 64 + i * 16 + lcol][quad * 8];
      const f16x8 af1 =
          *(const f16x8*)&sm.a.Xs[wr * 64 + i * 16 + lcol][32 + quad * 8];
#pragma unroll
      for (int j = 0; j < 4; ++j) {
        acc[i][j] = mfma16(af0, bf0[j], acc[i][j]);
        acc[i][j] = mfma16(af1, bf1[j], acc[i][j]);
      }
    }
  }

  if (which == 2) {
    // fp32 column sums -> Vsum (quad-reduced, register-only)
#pragma unroll
    for (int j = 0; j < 4; ++j) {
      float ps = 0.f;
#pragma unroll
      for (int i = 0; i < 4; ++i)
#pragma unroll
        for (int rr = 0; rr < 4; ++rr) ps += acc[i][j][rr];
      ps += __shfl_xor(ps, 16);
      ps += __shfl_xor(ps, 32);
      if (quad == 0) {
        const int d128 = wc * 64 + j * 16 + lcol;
        const int h = h0 + (d128 >> 6), d = d128 & 63;
        atomicAdd(&Vsum[((size_t)b * CH + h) * CDK + d], ps);
      }
    }
    // Ts[n][s]: packed f16x4 transpose writes, then coalesced V^T stores
    __syncthreads();
#pragma unroll
    for (int i = 0; i < 4; ++i)
#pragma unroll
      for (int j = 0; j < 4; ++j) {
        f16x4 v4;
#pragma unroll
        for (int rr = 0; rr < 4; ++rr) v4[rr] = (f16)acc[i][j][rr];
        *(f16x4*)&sm.Ts[wc * 64 + j * 16 + lcol][wr * 64 + i * 16 + quad * 4] =
            v4;
      }
    __syncthreads();
    const int c16 = t & 15;
#pragma unroll
    for (int p = 0; p < 8; ++p) {
      const int vr = p * 16 + (t >> 4);
      const int h = h0 + (vr >> 6), d = vr & 63;
      *(f16x8*)&Vth[(((size_t)b * CH + h) * CDK + d) * CS + s0 + c16 * 8] =
          *(const f16x8*)&sm.Ts[vr][c16 * 8];
    }
  } else {
    // Ts[s][n], then coalesced [B,H,S,64] stores (128-B runs)
    const float qsc = (which == 0) ? rsqrtf((float)lens[b]) * LOG2E : 1.0f;
    __syncthreads();
#pragma unroll
    for (int i = 0; i < 4; ++i)
#pragma unroll
      for (int j = 0; j < 4; ++j)
#pragma unroll
        for (int rr = 0; rr < 4; ++rr)
          sm.Ts[wr * 64 + i * 16 + quad * 4 + rr][wc * 64 + j * 16 + lcol] =
              (f16)(acc[i][j][rr] * qsc);
    __syncthreads();
    f16* O = (which == 0) ? Qh : Kh;
    const int c8 = t & 7;
#pragma unroll
    for (int p = 0; p < 4; ++p) {
      const int row = p * 32 + (t >> 3);
#pragma unroll
      for (int half = 0; half < 2; ++half) {
        const int h = h0 + half;
        *(f16x8*)&O[(((size_t)b * CH + h) * CS + s0 + row) * CDK + c8 * 8] =
            *(const f16x8*)&sm.Ts[row][half * 64 + c8 * 8];
      }
    }
  }
}

// ---------------------------------------------------------------------------
// Attention (MFMA flash; Q pre-scaled w/ log2e; exp2 softmax; reg-prefetch).
// NO early-exit (round-9 lesson: with 4-resident blocks/CU and no backfill,
// early-exited blocks permanently strand 4 waves of latency-hiding on their
// CU — occupancy 28.6%->16.9%, attn 60->74 us). All blocks run the tail-
// skipped nt loop; invalid rows overridden with Vsum/1024 in the epilogue.
// grid (8 q-tiles, 8 heads, 16 batch), block 256 = 4 waves x 32 q-rows.
// ---------------------------------------------------------------------------
__global__ __launch_bounds__(256) void attn_kernel(
    const f16* __restrict__ Qh, const f16* __restrict__ Kh,
    const f16* __restrict__ Vth, const int* __restrict__ lens,
    const float* __restrict__ Vsum, f16* __restrict__ Hbh) {
  const int qt = blockIdx.x, h = blockIdx.y, b = blockIdx.z;
  const int n = lens[b];
  const int t = threadIdx.x, w = t >> 6, lane = t & 63, quad = lane >> 4,
            lcol = lane & 15;

  const size_t bh = ((size_t)b * CH + h) * CS;
  const size_t bhd = ((size_t)b * CH + h) * CDK;

  const int nt = (n + 63) >> 6;

  __shared__ f16 Ks[64][72];     // [k][d]
  __shared__ f16 Vs[64][72];     // V^T: [d][k]
  __shared__ f16 Pt[4][32][72];  // wave-private P / O staging

  const int qbase = qt * 128 + w * 32;
  f16x8 qa[2][2];
#pragma unroll
  for (int set = 0; set < 2; ++set) {
    const size_t qr = bh + qbase + set * 16 + lcol;
    qa[set][0] = *(const f16x8*)&Qh[qr * CDK + quad * 8];
    qa[set][1] = *(const f16x8*)&Qh[qr * CDK + 32 + quad * 8];
  }

  f32x4 o[2][4];
#pragma unroll
  for (int set = 0; set < 2; ++set)
#pragma unroll
    for (int dt = 0; dt < 4; ++dt) o[set][dt] = (f32x4){0.f, 0.f, 0.f, 0.f};
  float lp[2][4] = {{0.f, 0.f, 0.f, 0.f}, {0.f, 0.f, 0.f, 0.f}};

  f16x8 pk[2], pv[2];
#pragma unroll
  for (int i = 0; i < 2; ++i) {
    const int c = t + 256 * i, r = c >> 3, sg = c & 7;
    pk[i] = *(const f16x8*)&Kh[(bh + r) * CDK + sg * 8];
    pv[i] = *(const f16x8*)&Vth[(bhd + r) * CS + sg * 8];
  }

  for (int kt = 0; kt < nt; ++kt) {
    __syncthreads();
#pragma unroll
    for (int i = 0; i < 2; ++i) {
      const int c = t + 256 * i, r = c >> 3, sg = c & 7;
      *(f16x8*)&Ks[r][sg * 8] = pk[i];
      *(f16x8*)&Vs[r][sg * 8] = pv[i];
    }
    __syncthreads();
    const int ktn = (kt + 1 < nt) ? kt + 1 : kt;
#pragma unroll
    for (int i = 0; i < 2; ++i) {
      const int c = t + 256 * i, r = c >> 3, sg = c & 7;
      pk[i] = *(const f16x8*)&Kh[(bh + ktn * 64 + r) * CDK + sg * 8];
      pv[i] = *(const f16x8*)&Vth[(bhd + r) * CS + ktn * 64 + sg * 8];
    }

    // QK + exp, set-serial (kb loaded per set: short VGPR lifetime)
#pragma unroll
    for (int set = 0; set < 2; ++set) {
      f32x4 st[4];
#pragma unroll
      for (int ct = 0; ct < 4; ++ct) {
        const f16x8 kb0 = *(const f16x8*)&Ks[ct * 16 + lcol][quad * 8];
        const f16x8 kb1 = *(const f16x8*)&Ks[ct * 16 + lcol][32 + quad * 8];
        st[ct] = mfma16(qa[set][0], kb0, (f32x4){0.f, 0.f, 0.f, 0.f});
        st[ct] = mfma16(qa[set][1], kb1, st[ct]);
      }
#pragma unroll
      for (int ct = 0; ct < 4; ++ct) {
        const bool kvld = (kt * 64 + ct * 16 + lcol) < n;
#pragma unroll
        for (int r = 0; r < 4; ++r) {
          float p = exp2f(st[ct][r]);
          p = kvld ? p : 0.f;
          lp[set][r] += p;
          Pt[w][set * 16 + quad * 4 + r][ct * 16 + lcol] = (f16)p;
        }
      }
    }

    f16x8 pa[2][2];
#pragma unroll
    for (int set = 0; set < 2; ++set) {
      pa[set][0] = *(const f16x8*)&Pt[w][set * 16 + lcol][quad * 8];
      pa[set][1] = *(const f16x8*)&Pt[w][set * 16 + lcol][32 + quad * 8];
    }

#pragma unroll
    for (int dt = 0; dt < 4; ++dt) {
      const f16x8 vb0 = *(const f16x8*)&Vs[dt * 16 + lcol][quad * 8];
      const f16x8 vb1 = *(const f16x8*)&Vs[dt * 16 + lcol][32 + quad * 8];
#pragma unroll
      for (int set = 0; set < 2; ++set) {
        o[set][dt] = mfma16(pa[set][0], vb0, o[set][dt]);
        o[set][dt] = mfma16(pa[set][1], vb1, o[set][dt]);
      }
    }
  }

  float invl[2][4];
#pragma unroll
  for (int set = 0; set < 2; ++set)
#pragma unroll
    for (int r = 0; r < 4; ++r) {
      float v = lp[set][r];
      v += __shfl_xor(v, 1);
      v += __shfl_xor(v, 2);
      v += __shfl_xor(v, 4);
      v += __shfl_xor(v, 8);
      invl[set][r] = 1.0f / v;
    }

  // O -> wave-private Pt (f16), then coalesced 128-B-run stores
#pragma unroll
  for (int set = 0; set < 2; ++set)
#pragma unroll
    for (int dt = 0; dt < 4; ++dt)
#pragma unroll
      for (int r = 0; r < 4; ++r) {
        const int srow_l = set * 16 + quad * 4 + r;
        const int d = dt * 16 + lcol;
        const float val = (qbase + srow_l < n)
                              ? o[set][dt][r] * invl[set][r]
                              : Vsum[bhd + d] * (1.0f / 1024.0f);
        Pt[w][srow_l][d] = (f16)val;
      }
  {
    const int lr = lane >> 3, lc = lane & 7;
#pragma unroll
    for (int p = 0; p < 4; ++p) {
      const int row = p * 8 + lr;
      *(f16x8*)&Hbh[((size_t)b * CS + qbase + row) * (CH * CDK) + h * CDK +
                    lc * 8] = *(const f16x8*)&Pt[w][row][lc * 8];
    }
  }
}

// ---------------------------------------------------------------------------
// Output projection: 128x128 tile, BK=64, global_load_lds staging (m97).
// grid (128 row-tiles, 4 col-tiles), block 256. LDS 32KB -> 5 blocks/CU.
// ---------------------------------------------------------------------------
__global__ __launch_bounds__(256) void outp_kernel(const f16* __restrict__ Hbh,
                                                   const f16* __restrict__ woutt,
                                                   float* __restrict__ out) {
  const int rt = blockIdx.x, ctile = blockIdx.y;
  const int row0 = rt * 128, col0 = ctile * 128;
  const f16* Wt = woutt + (size_t)col0 * CHID;
  const int t = threadIdx.x;
  const int w = t >> 6, lane = t & 63, quad = lane >> 4, lcol = lane & 15;
  const int wr = w >> 1, wc = w & 1;

  __shared__ f16 Hs[128][64];  // unpadded: lds-dma layout
  __shared__ f16 Ws[128][64];

  f32x4 acc[4][4];
#pragma unroll
  for (int i = 0; i < 4; ++i)
#pragma unroll
    for (int j = 0; j < 4; ++j) acc[i][j] = (f32x4){0.f, 0.f, 0.f, 0.f};

  for (int k0 = 0; k0 < CHID; k0 += 64) {
    __syncthreads();
#pragma unroll
    for (int i = 0; i < 4; ++i) {
      const int c = t + 256 * i, r = c >> 3, sg = c & 7;
      gld16(&Hbh[(size_t)(row0 + r) * CHID + k0 + sg * 8],
            (char*)&Hs[0][0] + c * 16);
      gld16(&Wt[(size_t)r * CHID + k0 + sg * 8], (char*)&Ws[0][0] + c * 16);
    }
    __syncthreads();

    f16x8 bf0[4], bf1[4];
#pragma unroll
    for (int j = 0; j < 4; ++j) {
      bf0[j] = *(const f16x8*)&Ws[wc * 64 + j * 16 + lcol][quad * 8];
      bf1[j] = *(const f16x8*)&Ws[wc * 64 + j * 16 + lcol][32 + quad * 8];
    }
#pragma unroll
    for (int i = 0; i < 4; ++i) {
      const f16x8 af0 = *(const f16x8*)&Hs[wr * 64 + i * 16 + lcol][quad * 8];
      const f16x8 af1 =
          *(const f16x8*)&Hs[wr * 64 + i * 16 + lcol][32 + quad * 8];
#pragma unroll
      for (int j = 0; j < 4; ++j) {
        acc[i][j] = mfma16(af0, bf0[j], acc[i][j]);
        acc[i][j] = mfma16(af1, bf1[j], acc[i][j]);
      }
    }
  }

#pragma unroll
  for (int i = 0; i < 4; ++i) {
#pragma unroll
    for (int rr = 0; rr < 4; ++rr) {
      const size_t rg = row0 + wr * 64 + i * 16 + quad * 4 + rr;
#pragma unroll
      for (int j = 0; j < 4; ++j)
        out[rg * CHID + col0 + wc * 64 + j * 16 + lcol] = acc[i][j][rr];
    }
  }
}

// ---------------------------------------------------------------------------
extern "C" void kernel_launch(void* const* d_in, const int* in_sizes, int n_in,
                              void* d_out, int out_size, void* d_ws,
                              size_t ws_size, hipStream_t stream) {
  const float* x = (const float*)d_in[0];
  const int* mask = (const int*)d_in[1];
  const float* Wq = (const float*)d_in[2];
  const float* Wk = (const float*)d_in[3];
  const float* Wv = (const float*)d_in[4];
  const float* Wout = (const float*)d_in[5];
  float* out = (float*)d_out;

  char* ws = (char*)d_ws;
  int* lens = (int*)ws;
  size_t off = 1024;
  const size_t NX = (size_t)CB * CS * CHID;   // 8,388,608
  const size_t NW = (size_t)CH * CHID * CDK;  // 262,144 per weight
  f16* xh = (f16*)(ws + off);    off += NX * 2;
  f16* wtAll = (f16*)(ws + off); off += NW * 4 * 2;
  f16* Qh = (f16*)(ws + off);    off += NX * 2;
  f16* Kh = (f16*)(ws + off);    off += NX * 2;
  f16* Vth = (f16*)(ws + off);   off += NX * 2;
  f16* Hbh = (f16*)(ws + off);   off += NX * 2;
  float* Vsum = (float*)(ws + off); off += (size_t)CB * CH * CDK * 4;
  f16* woutt = wtAll + NW * 3;

  prep_kernel<<<8208, 256, 0, stream>>>((const float4*)x, (f16x4*)xh, mask,
                                        lens, Vsum);
  cast_w_kernel<<<dim3(8, 32), 256, 0, stream>>>(Wq, Wk, Wv, Wout, wtAll);
  qkvf_kernel<<<dim3(12, 128), 256, 0, stream>>>(xh, wtAll, lens, Qh, Kh, Vth,
                                                 Vsum);
  attn_kernel<<<dim3(CS / 128, CH, CB), 256, 0, stream>>>(Qh, Kh, Vth, lens,
                                                          Vsum, Hbh);
  outp_kernel<<<dim3(128, 4), 256, 0, stream>>>(Hbh, woutt, out);
}

// Round 11
// 201.761 us; speedup vs baseline: 1.1216x; 1.0967x over previous
//
#include <hip/hip_runtime.h>
#include <math.h>

// QANetAttBlock: B=16, S=1024, HID=512, H=8, DK=64
constexpr int CB = 16;
constexpr int CS = 1024;
constexpr int CHID = 512;
constexpr int CH = 8;
constexpr int CDK = 64;

typedef _Float16 f16;
typedef __attribute__((ext_vector_type(8))) _Float16 f16x8;
typedef __attribute__((ext_vector_type(4))) _Float16 f16x4;
typedef __attribute__((ext_vector_type(4))) float f32x4;

__device__ inline f32x4 mfma16(f16x8 a, f16x8 b, f32x4 c) {
  return __builtin_amdgcn_mfma_f32_16x16x32_f16(a, b, c, 0, 0, 0);
}

// async global->LDS, 16B per lane; dest must be wave-uniform base + lane*16
__device__ inline void gld16(const void* g, void* l) {
  __builtin_amdgcn_global_load_lds(
      (const __attribute__((address_space(1))) void*)g,
      (__attribute__((address_space(3))) void*)l, 16, 0, 0);
}

// raw v_exp_f32 (2^x). libm exp2f costs ~10 extra VALU/call (r10 lesson:
// attn 60->76us was exp2f vs __expf).
__device__ inline float fast_exp2(float x) {
#if __has_builtin(__builtin_amdgcn_exp2f)
  return __builtin_amdgcn_exp2f(x);
#else
  return __expf(x * 0.6931471805599453f);
#endif
}

#define LOG2E 1.4426950408889634f

// ---------------------------------------------------------------------------
// prep: blocks 0..8191 cast x fp32->fp16; blocks 8192..8207 compute lens[b]
// and zero Vsum (ws is poisoned 0xAA).
// ---------------------------------------------------------------------------
__global__ __launch_bounds__(256) void prep_kernel(const float4* __restrict__ x,
                                                   f16x4* __restrict__ xh,
                                                   const int* __restrict__ mask,
                                                   int* __restrict__ lens,
                                                   float* __restrict__ Vsum) {
  const int bid = blockIdx.x, t = threadIdx.x;
  __shared__ int red[256];
  if (bid < 8192) {
    const int idx = bid * 256 + t;
    const float4 v = x[idx];
    f16x4 o;
    o[0] = (f16)v.x; o[1] = (f16)v.y; o[2] = (f16)v.z; o[3] = (f16)v.w;
    xh[idx] = o;
  } else {
    const int b = bid - 8192;
    const int g = b * 256 + t;
    Vsum[g * 2] = 0.f;
    Vsum[g * 2 + 1] = 0.f;
    int s = 0;
    for (int i = t; i < CS; i += 256) s += mask[b * CS + i];
    red[t] = s;
    __syncthreads();
    for (int off = 128; off > 0; off >>= 1) {
      if (t < off) red[t] += red[t + off];
      __syncthreads();
    }
    if (t == 0) lens[b] = red[0];
  }
}

// ---------------------------------------------------------------------------
// cast + transpose weights via LDS (coalesced fp32 reads).
// ---------------------------------------------------------------------------
__global__ __launch_bounds__(256) void cast_w_kernel(const float* __restrict__ Wq,
                                                     const float* __restrict__ Wk,
                                                     const float* __restrict__ Wv,
                                                     const float* __restrict__ Wout,
                                                     f16* __restrict__ wtAll) {
  const int y = blockIdx.y, kb = blockIdx.x, t = threadIdx.x;
  const int k0 = kb * 64;
  const float* src;
  int ldsrc;
  f16* dst;
  if (y < 24) {
    const int which = y >> 3, h = y & 7;
    const float* W = (which == 0) ? Wq : (which == 1) ? Wk : Wv;
    src = W + (size_t)h * 32768 + (size_t)k0 * 64;
    ldsrc = 64;
    dst = wtAll + (size_t)which * 262144 + (size_t)h * 32768;
  } else {
    const int c = y - 24;
    src = Wout + (size_t)k0 * 512 + c * 64;
    ldsrc = 512;
    dst = wtAll + (size_t)3 * 262144 + (size_t)c * 64 * 512;
  }

  __shared__ float Ts[64][68];
  {
    const int kr = t >> 4, cg = (t & 15) * 4;
#pragma unroll
    for (int rr = 0; rr < 4; ++rr) {
      const float4 v = *(const float4*)&src[(size_t)(rr * 16 + kr) * ldsrc + cg];
      Ts[rr * 16 + kr][cg] = v.x;
      Ts[rr * 16 + kr][cg + 1] = v.y;
      Ts[rr * 16 + kr][cg + 2] = v.z;
      Ts[rr * 16 + kr][cg + 3] = v.w;
    }
  }
  __syncthreads();
  {
    const int n = t >> 2, seg = t & 3;
    f16x8 a, b;
#pragma unroll
    for (int j = 0; j < 8; ++j) {
      a[j] = (f16)Ts[seg * 16 + j][n];
      b[j] = (f16)Ts[seg * 16 + 8 + j][n];
    }
    f16* d = &dst[(size_t)n * 512 + k0 + seg * 16];
    *(f16x8*)d = a;
    *(f16x8*)(d + 8) = b;
  }
}

// ---------------------------------------------------------------------------
// Fused QKV projection: 128x128 tile, BK=64, gld16 staging with XOR column
// swizzle (physical chunk p of row r holds logical chunk p^(r&7); frag reads
// use chunk quad^(row&7) -> 2-way banks instead of 16-way on unpadded LDS).
// grid (12 col-tiles, 128 row-tiles). Q pre-scaled by log2e/sqrt(n[b]);
// epilogues via padded Ts union, coalesced. V: fp32 col sums -> Vsum.
// ---------------------------------------------------------------------------
__global__ __launch_bounds__(256) void qkvf_kernel(
    const f16* __restrict__ xh, const f16* __restrict__ wtAll,
    const int* __restrict__ lens, f16* __restrict__ Qh, f16* __restrict__ Kh,
    f16* __restrict__ Vth, float* __restrict__ Vsum) {
  const int ct = blockIdx.x, rt = blockIdx.y;
  const int which = ct >> 2, hp = ct & 3;
  const f16* Wt = wtAll + (size_t)which * 262144 + (size_t)hp * 65536;
  const int row0 = rt * 128;
  const int b = row0 >> 10, s0 = row0 & 1023;
  const int h0 = hp * 2;
  const int t = threadIdx.x;
  const int w = t >> 6, lane = t & 63, quad = lane >> 4, lcol = lane & 15;
  const int wr = w >> 1, wc = w & 1;

  __shared__ union SM {
    struct { f16 Xs[128][64]; f16 Ws[128][64]; } a;  // unpadded (lds-dma)
    f16 Ts[128][136];                                // epilogue staging
  } sm;

  f32x4 acc[4][4];
#pragma unroll
  for (int i = 0; i < 4; ++i)
#pragma unroll
    for (int j = 0; j < 4; ++j) acc[i][j] = (f32x4){0.f, 0.f, 0.f, 0.f};

  for (int k0 = 0; k0 < CHID; k0 += 64) {
    __syncthreads();  // prior compute's LDS reads done
#pragma unroll
    for (int i = 0; i < 4; ++i) {
      const int c = t + 256 * i, r = c >> 3, sg = c & 7;
      const int gsw = (sg ^ (r & 7)) * 8;  // XOR swizzle on global source
      gld16(&xh[(size_t)(row0 + r) * CHID + k0 + gsw],
            (char*)&sm.a.Xs[0][0] + c * 16);
      gld16(&Wt[(size_t)r * CHID + k0 + gsw], (char*)&sm.a.Ws[0][0] + c * 16);
    }
    __syncthreads();  // drains vmcnt: LDS tiles ready

    f16x8 bf0[4], bf1[4];
#pragma unroll
    for (int j = 0; j < 4; ++j) {
      const int br = wc * 64 + j * 16 + lcol;
      bf0[j] = *(const f16x8*)&sm.a.Ws[br][(quad ^ (br & 7)) * 8];
      bf1[j] = *(const f16x8*)&sm.a.Ws[br][((quad ^ 4) ^ (br & 7)) * 8];
    }
#pragma unroll
    for (int i = 0; i < 4; ++i) {
      const int ar = wr * 64 + i * 16 + lcol;
      const f16x8 af0 = *(const f16x8*)&sm.a.Xs[ar][(quad ^ (ar & 7)) * 8];
      const f16x8 af1 =
          *(const f16x8*)&sm.a.Xs[ar][((quad ^ 4) ^ (ar & 7)) * 8];
#pragma unroll
      for (int j = 0; j < 4; ++j) {
        acc[i][j] = mfma16(af0, bf0[j], acc[i][j]);
        acc[i][j] = mfma16(af1, bf1[j], acc[i][j]);
      }
    }
  }

  if (which == 2) {
    // fp32 column sums -> Vsum (quad-reduced, register-only)
#pragma unroll
    for (int j = 0; j < 4; ++j) {
      float ps = 0.f;
#pragma unroll
      for (int i = 0; i < 4; ++i)
#pragma unroll
        for (int rr = 0; rr < 4; ++rr) ps += acc[i][j][rr];
      ps += __shfl_xor(ps, 16);
      ps += __shfl_xor(ps, 32);
      if (quad == 0) {
        const int d128 = wc * 64 + j * 16 + lcol;
        const int h = h0 + (d128 >> 6), d = d128 & 63;
        atomicAdd(&Vsum[((size_t)b * CH + h) * CDK + d], ps);
      }
    }
    // Ts[n][s]: packed f16x4 transpose writes, then coalesced V^T stores
    __syncthreads();
#pragma unroll
    for (int i = 0; i < 4; ++i)
#pragma unroll
      for (int j = 0; j < 4; ++j) {
        f16x4 v4;
#pragma unroll
        for (int rr = 0; rr < 4; ++rr) v4[rr] = (f16)acc[i][j][rr];
        *(f16x4*)&sm.Ts[wc * 64 + j * 16 + lcol][wr * 64 + i * 16 + quad * 4] =
            v4;
      }
    __syncthreads();
    const int c16 = t & 15;
#pragma unroll
    for (int p = 0; p < 8; ++p) {
      const int vr = p * 16 + (t >> 4);
      const int h = h0 + (vr >> 6), d = vr & 63;
      *(f16x8*)&Vth[(((size_t)b * CH + h) * CDK + d) * CS + s0 + c16 * 8] =
          *(const f16x8*)&sm.Ts[vr][c16 * 8];
    }
  } else {
    // Ts[s][n], then coalesced [B,H,S,64] stores (128-B runs)
    const float qsc = (which == 0) ? rsqrtf((float)lens[b]) * LOG2E : 1.0f;
    __syncthreads();
#pragma unroll
    for (int i = 0; i < 4; ++i)
#pragma unroll
      for (int j = 0; j < 4; ++j)
#pragma unroll
        for (int rr = 0; rr < 4; ++rr)
          sm.Ts[wr * 64 + i * 16 + quad * 4 + rr][wc * 64 + j * 16 + lcol] =
              (f16)(acc[i][j][rr] * qsc);
    __syncthreads();
    f16* O = (which == 0) ? Qh : Kh;
    const int c8 = t & 7;
#pragma unroll
    for (int p = 0; p < 4; ++p) {
      const int row = p * 32 + (t >> 3);
#pragma unroll
      for (int half = 0; half < 2; ++half) {
        const int h = h0 + half;
        *(f16x8*)&O[(((size_t)b * CH + h) * CS + s0 + row) * CDK + c8 * 8] =
            *(const f16x8*)&sm.Ts[row][half * 64 + c8 * 8];
      }
    }
  }
}

// ---------------------------------------------------------------------------
// Attention (MFMA flash; Q pre-scaled w/ log2e; v_exp_f32 softmax;
// reg-prefetch K/V; tail k-tiles skipped; invalid rows -> Vsum/1024).
// No early-exit, no kb hoist (r8/r9 lessons). grid (8,8,16), block 256.
// ---------------------------------------------------------------------------
__global__ __launch_bounds__(256) void attn_kernel(
    const f16* __restrict__ Qh, const f16* __restrict__ Kh,
    const f16* __restrict__ Vth, const int* __restrict__ lens,
    const float* __restrict__ Vsum, f16* __restrict__ Hbh) {
  const int qt = blockIdx.x, h = blockIdx.y, b = blockIdx.z;
  const int n = lens[b];
  const int t = threadIdx.x, w = t >> 6, lane = t & 63, quad = lane >> 4,
            lcol = lane & 15;

  const size_t bh = ((size_t)b * CH + h) * CS;
  const size_t bhd = ((size_t)b * CH + h) * CDK;

  const int nt = (n + 63) >> 6;

  __shared__ f16 Ks[64][72];     // [k][d]
  __shared__ f16 Vs[64][72];     // V^T: [d][k]
  __shared__ f16 Pt[4][32][72];  // wave-private P / O staging

  const int qbase = qt * 128 + w * 32;
  f16x8 qa[2][2];
#pragma unroll
  for (int set = 0; set < 2; ++set) {
    const size_t qr = bh + qbase + set * 16 + lcol;
    qa[set][0] = *(const f16x8*)&Qh[qr * CDK + quad * 8];
    qa[set][1] = *(const f16x8*)&Qh[qr * CDK + 32 + quad * 8];
  }

  f32x4 o[2][4];
#pragma unroll
  for (int set = 0; set < 2; ++set)
#pragma unroll
    for (int dt = 0; dt < 4; ++dt) o[set][dt] = (f32x4){0.f, 0.f, 0.f, 0.f};
  float lp[2][4] = {{0.f, 0.f, 0.f, 0.f}, {0.f, 0.f, 0.f, 0.f}};

  f16x8 pk[2], pv[2];
#pragma unroll
  for (int i = 0; i < 2; ++i) {
    const int c = t + 256 * i, r = c >> 3, sg = c & 7;
    pk[i] = *(const f16x8*)&Kh[(bh + r) * CDK + sg * 8];
    pv[i] = *(const f16x8*)&Vth[(bhd + r) * CS + sg * 8];
  }

  for (int kt = 0; kt < nt; ++kt) {
    __syncthreads();
#pragma unroll
    for (int i = 0; i < 2; ++i) {
      const int c = t + 256 * i, r = c >> 3, sg = c & 7;
      *(f16x8*)&Ks[r][sg * 8] = pk[i];
      *(f16x8*)&Vs[r][sg * 8] = pv[i];
    }
    __syncthreads();
    const int ktn = (kt + 1 < nt) ? kt + 1 : kt;
#pragma unroll
    for (int i = 0; i < 2; ++i) {
      const int c = t + 256 * i, r = c >> 3, sg = c & 7;
      pk[i] = *(const f16x8*)&Kh[(bh + ktn * 64 + r) * CDK + sg * 8];
      pv[i] = *(const f16x8*)&Vth[(bhd + r) * CS + ktn * 64 + sg * 8];
    }

    // QK + exp, set-serial (kb loaded per set: short VGPR lifetime)
#pragma unroll
    for (int set = 0; set < 2; ++set) {
      f32x4 st[4];
#pragma unroll
      for (int ct = 0; ct < 4; ++ct) {
        const f16x8 kb0 = *(const f16x8*)&Ks[ct * 16 + lcol][quad * 8];
        const f16x8 kb1 = *(const f16x8*)&Ks[ct * 16 + lcol][32 + quad * 8];
        st[ct] = mfma16(qa[set][0], kb0, (f32x4){0.f, 0.f, 0.f, 0.f});
        st[ct] = mfma16(qa[set][1], kb1, st[ct]);
      }
#pragma unroll
      for (int ct = 0; ct < 4; ++ct) {
        const bool kvld = (kt * 64 + ct * 16 + lcol) < n;
#pragma unroll
        for (int r = 0; r < 4; ++r) {
          float p = fast_exp2(st[ct][r]);
          p = kvld ? p : 0.f;
          lp[set][r] += p;
          Pt[w][set * 16 + quad * 4 + r][ct * 16 + lcol] = (f16)p;
        }
      }
    }

    f16x8 pa[2][2];
#pragma unroll
    for (int set = 0; set < 2; ++set) {
      pa[set][0] = *(const f16x8*)&Pt[w][set * 16 + lcol][quad * 8];
      pa[set][1] = *(const f16x8*)&Pt[w][set * 16 + lcol][32 + quad * 8];
    }

#pragma unroll
    for (int dt = 0; dt < 4; ++dt) {
      const f16x8 vb0 = *(const f16x8*)&Vs[dt * 16 + lcol][quad * 8];
      const f16x8 vb1 = *(const f16x8*)&Vs[dt * 16 + lcol][32 + quad * 8];
#pragma unroll
      for (int set = 0; set < 2; ++set) {
        o[set][dt] = mfma16(pa[set][0], vb0, o[set][dt]);
        o[set][dt] = mfma16(pa[set][1], vb1, o[set][dt]);
      }
    }
  }

  float invl[2][4];
#pragma unroll
  for (int set = 0; set < 2; ++set)
#pragma unroll
    for (int r = 0; r < 4; ++r) {
      float v = lp[set][r];
      v += __shfl_xor(v, 1);
      v += __shfl_xor(v, 2);
      v += __shfl_xor(v, 4);
      v += __shfl_xor(v, 8);
      invl[set][r] = 1.0f / v;
    }

  // O -> wave-private Pt (f16), then coalesced 128-B-run stores
#pragma unroll
  for (int set = 0; set < 2; ++set)
#pragma unroll
    for (int dt = 0; dt < 4; ++dt)
#pragma unroll
      for (int r = 0; r < 4; ++r) {
        const int srow_l = set * 16 + quad * 4 + r;
        const int d = dt * 16 + lcol;
        const float val = (qbase + srow_l < n)
                              ? o[set][dt][r] * invl[set][r]
                              : Vsum[bhd + d] * (1.0f / 1024.0f);
        Pt[w][srow_l][d] = (f16)val;
      }
  {
    const int lr = lane >> 3, lc = lane & 7;
#pragma unroll
    for (int p = 0; p < 4; ++p) {
      const int row = p * 8 + lr;
      *(f16x8*)&Hbh[((size_t)b * CS + qbase + row) * (CH * CDK) + h * CDK +
                    lc * 8] = *(const f16x8*)&Pt[w][row][lc * 8];
    }
  }
}

// ---------------------------------------------------------------------------
// Output projection: 128x128 tile, BK=64, gld16 + XOR swizzle (as qkvf).
// grid (128 row-tiles, 4 col-tiles), block 256.
// ---------------------------------------------------------------------------
__global__ __launch_bounds__(256) void outp_kernel(const f16* __restrict__ Hbh,
                                                   const f16* __restrict__ woutt,
                                                   float* __restrict__ out) {
  const int rt = blockIdx.x, ctile = blockIdx.y;
  const int row0 = rt * 128, col0 = ctile * 128;
  const f16* Wt = woutt + (size_t)col0 * CHID;
  const int t = threadIdx.x;
  const int w = t >> 6, lane = t & 63, quad = lane >> 4, lcol = lane & 15;
  const int wr = w >> 1, wc = w & 1;

  __shared__ f16 Hs[128][64];  // unpadded (lds-dma), XOR-swizzled columns
  __shared__ f16 Ws[128][64];

  f32x4 acc[4][4];
#pragma unroll
  for (int i = 0; i < 4; ++i)
#pragma unroll
    for (int j = 0; j < 4; ++j) acc[i][j] = (f32x4){0.f, 0.f, 0.f, 0.f};

  for (int k0 = 0; k0 < CHID; k0 += 64) {
    __syncthreads();
#pragma unroll
    for (int i = 0; i < 4; ++i) {
      const int c = t + 256 * i, r = c >> 3, sg = c & 7;
      const int gsw = (sg ^ (r & 7)) * 8;
      gld16(&Hbh[(size_t)(row0 + r) * CHID + k0 + gsw],
            (char*)&Hs[0][0] + c * 16);
      gld16(&Wt[(size_t)r * CHID + k0 + gsw], (char*)&Ws[0][0] + c * 16);
    }
    __syncthreads();

    f16x8 bf0[4], bf1[4];
#pragma unroll
    for (int j = 0; j < 4; ++j) {
      const int br = wc * 64 + j * 16 + lcol;
      bf0[j] = *(const f16x8*)&Ws[br][(quad ^ (br & 7)) * 8];
      bf1[j] = *(const f16x8*)&Ws[br][((quad ^ 4) ^ (br & 7)) * 8];
    }
#pragma unroll
    for (int i = 0; i < 4; ++i) {
      const int ar = wr * 64 + i * 16 + lcol;
      const f16x8 af0 = *(const f16x8*)&Hs[ar][(quad ^ (ar & 7)) * 8];
      const f16x8 af1 = *(const f16x8*)&Hs[ar][((quad ^ 4) ^ (ar & 7)) * 8];
#pragma unroll
      for (int j = 0; j < 4; ++j) {
        acc[i][j] = mfma16(af0, bf0[j], acc[i][j]);
        acc[i][j] = mfma16(af1, bf1[j], acc[i][j]);
      }
    }
  }

#pragma unroll
  for (int i = 0; i < 4; ++i) {
#pragma unroll
    for (int rr = 0; rr < 4; ++rr) {
      const size_t rg = row0 + wr * 64 + i * 16 + quad * 4 + rr;
#pragma unroll
      for (int j = 0; j < 4; ++j)
        out[rg * CHID + col0 + wc * 64 + j * 16 + lcol] = acc[i][j][rr];
    }
  }
}

// ---------------------------------------------------------------------------
extern "C" void kernel_launch(void* const* d_in, const int* in_sizes, int n_in,
                              void* d_out, int out_size, void* d_ws,
                              size_t ws_size, hipStream_t stream) {
  const float* x = (const float*)d_in[0];
  const int* mask = (const int*)d_in[1];
  const float* Wq = (const float*)d_in[2];
  const float* Wk = (const float*)d_in[3];
  const float* Wv = (const float*)d_in[4];
  const float* Wout = (const float*)d_in[5];
  float* out = (float*)d_out;

  char* ws = (char*)d_ws;
  int* lens = (int*)ws;
  size_t off = 1024;
  const size_t NX = (size_t)CB * CS * CHID;   // 8,388,608
  const size_t NW = (size_t)CH * CHID * CDK;  // 262,144 per weight
  f16* xh = (f16*)(ws + off);    off += NX * 2;
  f16* wtAll = (f16*)(ws + off); off += NW * 4 * 2;
  f16* Qh = (f16*)(ws + off);    off += NX * 2;
  f16* Kh = (f16*)(ws + off);    off += NX * 2;
  f16* Vth = (f16*)(ws + off);   off += NX * 2;
  f16* Hbh = (f16*)(ws + off);   off += NX * 2;
  float* Vsum = (float*)(ws + off); off += (size_t)CB * CH * CDK * 4;
  f16* woutt = wtAll + NW * 3;

  prep_kernel<<<8208, 256, 0, stream>>>((const float4*)x, (f16x4*)xh, mask,
                                        lens, Vsum);
  cast_w_kernel<<<dim3(8, 32), 256, 0, stream>>>(Wq, Wk, Wv, Wout, wtAll);
  qkvf_kernel<<<dim3(12, 128), 256, 0, stream>>>(xh, wtAll, lens, Qh, Kh, Vth,
                                                 Vsum);
  attn_kernel<<<dim3(CS / 128, CH, CB), 256, 0, stream>>>(Qh, Kh, Vth, lens,
                                                          Vsum, Hbh);
  outp_kernel<<<dim3(128, 4), 256, 0, stream>>>(Hbh, woutt, out);
}